// Round 7
// baseline (1239.787 us; speedup 1.0000x reference)
//
#include <hip/hip_runtime.h>
#include <math.h>

// Problem constants (reference: B=32, L=2048)
#define LLEN 2048
#define BATCH 32
#define N_PTS (LLEN - 2)     // 2046 embedded points
#define N_DEATH (LLEN - 3)   // 2045 MST edges / deaths
#define SORT_N 2048
#define TPB 256              // 4 waves, one per SIMD
#define PT 8                 // elements per thread
#define NW 4                 // waves per block
#define BIG 1e30f

// Wave64 unsigned-min via DPP (VALU pipe). Result valid in lane 63.
__device__ __forceinline__ unsigned dpp_umin6(unsigned v) {
    unsigned t;
    t = (unsigned)__builtin_amdgcn_update_dpp(-1, (int)v, 0x111, 0xF, 0xF, false); // row_shr:1
    v = t < v ? t : v;
    t = (unsigned)__builtin_amdgcn_update_dpp(-1, (int)v, 0x112, 0xF, 0xF, false); // row_shr:2
    v = t < v ? t : v;
    t = (unsigned)__builtin_amdgcn_update_dpp(-1, (int)v, 0x114, 0xF, 0xF, false); // row_shr:4
    v = t < v ? t : v;
    t = (unsigned)__builtin_amdgcn_update_dpp(-1, (int)v, 0x118, 0xF, 0xF, false); // row_shr:8
    v = t < v ? t : v;
    t = (unsigned)__builtin_amdgcn_update_dpp(-1, (int)v, 0x142, 0xF, 0xF, false); // row_bcast:15
    v = t < v ? t : v;
    t = (unsigned)__builtin_amdgcn_update_dpp(-1, (int)v, 0x143, 0xF, 0xF, false); // row_bcast:31
    v = t < v ? t : v;
    return v;
}

// One block per series. Prim with packed (d2|idx) u32 candidates; lock-free
// polled LDS mailbox (tag protocol + bit-11 sentinel clear proven r4/r5).
// Winner's coords travel through the mailbox (pp[j] broadcast read deleted).
// ROUND-7 FIXES for the r6 regression:
//   * __launch_bounds__(TPB, 1): real occupancy is 1 block/CU (64 blocks on
//     256 CUs), so tell the allocator — r6's default budget spilled px/py/pz/m
//     to scratch (VGPR_Count 32!) and put ~200-cyc scratch loads in the scan.
//   * single-lane publish via ballot+ffs: r6's `lv==smin` predicate was true
//     on ALL 64 lanes of an all-visited wave (late-Prim common case) -> 64
//     same-address ds_write_b128 storms. Now exactly one lane writes.
__global__ __launch_bounds__(TPB, 1)
void topo_kernel(const float* __restrict__ pred,
                 const float* __restrict__ tgt,
                 float* __restrict__ topo /* [64][N_DEATH] */) {
    __shared__ float deaths[SORT_N];     // raw d2 during Prim
    __shared__ uint4 xslot[2 * NW];      // mailbox [buf][wave]: val|tag,x,y,z

    const int b = blockIdx.x;
    const float* x = (b < BATCH) ? (pred + b * LLEN) : (tgt + (b - BATCH) * LLEN);
    const int t = threadIdx.x;
    const int lane = t & 63;
    const int wid = t >> 6;

    // mailbox init: tag bit = 1 mismatches iteration 0/1's expected tag 0
    if (t < 2 * NW) xslot[t] = make_uint4(0x800u, 0u, 0u, 0u);

    float px[PT], py[PT], pz[PT];
    unsigned m[PT];      // packed running min-distance (d2_hi20 | 0 | idx)
    unsigned idxs[PT];
    unsigned vis = 0;    // bit s: vertex t*PT+s is visited (or padding)
#pragma unroll
    for (int s = 0; s < PT; ++s) {
        int idx = t * PT + s;
        idxs[s] = (unsigned)idx;
        bool valid = idx < N_PTS;
        px[s] = valid ? x[idx]     : 0.f;
        py[s] = valid ? x[idx + 1] : 0.f;
        pz[s] = valid ? x[idx + 2] : 0.f;
        m[s] = 0x7F800000u | idxs[s];           // +inf packed
        if (!valid || idx == 0) vis |= 1u << s; // pads + start vertex visited
    }
    __syncthreads();   // mailbox init visible (only barrier before sort)

    float pjx = x[0], pjy = x[1], pjz = x[2];

    for (int i = 0; i < N_DEATH; ++i) {
        // fused: min-update with distance to j + masked local argmin.
        unsigned lv0 = 0xFFFFFFFFu, lv1 = 0xFFFFFFFFu;
#pragma unroll
        for (int s = 0; s < PT; ++s) {
            float dx = px[s] - pjx, dy = py[s] - pjy, dz = pz[s] - pjz;
            float d2 = dx * dx + dy * dy + dz * dz;
            unsigned pk = (__float_as_uint(d2) & 0xFFFFF000u) | idxs[s]; // v_and_or
            unsigned nm = m[s] < pk ? m[s] : pk;
            m[s] = nm;
            unsigned ext = (unsigned)__builtin_amdgcn_sbfe((int)vis, s, 1);
            unsigned cand = nm | ext;
            if (s & 1) lv1 = lv1 < cand ? lv1 : cand;
            else       lv0 = lv0 < cand ? lv0 : cand;
        }
        unsigned lv = lv0 < lv1 ? lv0 : lv1;
        unsigned wmin = dpp_umin6(lv);           // valid in lane 63
        unsigned smin = (unsigned)__builtin_amdgcn_readlane((int)wmin, 63);
        // exactly one publishing lane, even when the whole wave is visited
        unsigned long long mk = __ballot(lv == smin);
        int wl = __ffsll(mk) - 1;

        // local coord select: sel = lv & 7 (idx low bits == element slot).
        // 3-level cndmask tree; issue overlaps the DPP/ballot latency.
        unsigned sel = lv & 7u;
        float ax0 = (sel & 1) ? px[1] : px[0], ax1 = (sel & 1) ? px[3] : px[2];
        float ax2 = (sel & 1) ? px[5] : px[4], ax3 = (sel & 1) ? px[7] : px[6];
        float ay0 = (sel & 1) ? py[1] : py[0], ay1 = (sel & 1) ? py[3] : py[2];
        float ay2 = (sel & 1) ? py[5] : py[4], ay3 = (sel & 1) ? py[7] : py[6];
        float az0 = (sel & 1) ? pz[1] : pz[0], az1 = (sel & 1) ? pz[3] : pz[2];
        float az2 = (sel & 1) ? pz[5] : pz[4], az3 = (sel & 1) ? pz[7] : pz[6];
        float bx0 = (sel & 2) ? ax1 : ax0, bx1 = (sel & 2) ? ax3 : ax2;
        float by0 = (sel & 2) ? ay1 : ay0, by1 = (sel & 2) ? ay3 : ay2;
        float bz0 = (sel & 2) ? az1 : az0, bz1 = (sel & 2) ? az3 : az2;
        float cx = (sel & 4) ? bx1 : bx0;
        float cy = (sel & 4) ? by1 : by0;
        float cz = (sel & 4) ? bz1 : bz0;

        const unsigned tag = ((unsigned)(i >> 1) & 1u) << 11;
        const int base = (i & 1) * NW;
        // winner lane publishes value+coords (bit 11 cleared, tag stamped)
        if (lane == wl) {
            xslot[base + wid] = make_uint4((lv & 0xFFFFF7FFu) | tag,
                                           __float_as_uint(cx),
                                           __float_as_uint(cy),
                                           __float_as_uint(cz));
        }
        // poll: 4 plain b128 loads back-to-back, one waitcnt per round
        uint4 v0, v1, v2, v3;
        for (;;) {
            __asm__ __volatile__("" ::: "memory");
            v0 = xslot[base + 0]; v1 = xslot[base + 1];
            v2 = xslot[base + 2]; v3 = xslot[base + 3];
            unsigned bad = ((v0.x ^ tag) | (v1.x ^ tag) |
                            (v2.x ^ tag) | (v3.x ^ tag)) & 0x800u;
            if (!bad) break;
        }
        // 4-way tournament carrying coords (tags equal -> compare unaffected)
        bool b01 = v0.x < v1.x;
        unsigned w01v = b01 ? v0.x : v1.x;
        float w01x = b01 ? __uint_as_float(v0.y) : __uint_as_float(v1.y);
        float w01y = b01 ? __uint_as_float(v0.z) : __uint_as_float(v1.z);
        float w01z = b01 ? __uint_as_float(v0.w) : __uint_as_float(v1.w);
        bool b23 = v2.x < v3.x;
        unsigned w23v = b23 ? v2.x : v3.x;
        float w23x = b23 ? __uint_as_float(v2.y) : __uint_as_float(v3.y);
        float w23y = b23 ? __uint_as_float(v2.z) : __uint_as_float(v3.z);
        float w23z = b23 ? __uint_as_float(v2.w) : __uint_as_float(v3.w);
        bool bw = w01v < w23v;
        unsigned winv = bw ? w01v : w23v;
        pjx = bw ? w01x : w23x;
        pjy = bw ? w01y : w23y;
        pjz = bw ? w01z : w23z;
        int j = (int)(winv & 0x7FFu);
        // mark new j visited in its owner thread
        vis |= (t == (j >> 3)) ? (1u << (j & 7)) : 0u;
        if (t == 0) deaths[i] = __uint_as_float(winv & 0xFFFFF000u); // raw d2
    }

    // pad then bitonic sort DESCENDING on d2 (sqrt is monotone -> same order)
    if (t < SORT_N - N_DEATH) deaths[N_DEATH + t] = -BIG;
    __syncthreads();

    for (int k = 2; k <= SORT_N; k <<= 1) {
        for (int jj = k >> 1; jj > 0; jj >>= 1) {
#pragma unroll
            for (int s = 0; s < SORT_N / TPB; ++s) {
                int ii = t + s * TPB;
                int ixj = ii ^ jj;
                if (ixj > ii) {
                    float a = deaths[ii], c = deaths[ixj];
                    bool descBlock = ((ii & k) == 0);
                    bool doSwap = descBlock ? (a < c) : (a > c);
                    if (doSwap) { deaths[ii] = c; deaths[ixj] = a; }
                }
            }
            __syncthreads();
        }
    }

    for (int e = t; e < N_DEATH; e += TPB)
        topo[b * N_DEATH + e] = sqrtf(deaths[e]);   // sqrt deferred to here
}

// Two-stage loss (used when d_ws has room for the 512 B partials buffer)
__global__ __launch_bounds__(256)
void partial_loss(const float* __restrict__ pred,
                  const float* __restrict__ tgt,
                  const float* __restrict__ topo,
                  float2* __restrict__ part) {
    const int t = threadIdx.x;
    const int gid = blockIdx.x * 256 + t;       // 0..16383
    const float4* p4 = (const float4*)pred;
    const float4* t4 = (const float4*)tgt;
    float4 a = p4[gid], c = t4[gid];            // exactly one float4 per thread
    float dx = a.x - c.x, dy = a.y - c.y, dz = a.z - c.z, dw = a.w - c.w;
    float msum = dx * dx + dy * dy + dz * dz + dw * dw;
    float tsum = 0.f;
    const int nt = BATCH * N_DEATH;             // 65440
    for (int e = gid; e < nt; e += 64 * 256) {
        float d = topo[e] - topo[e + nt];
        tsum += d * d;
    }
    __shared__ float sm[2][4];
#pragma unroll
    for (int off = 32; off >= 1; off >>= 1) {
        msum += __shfl_xor(msum, off);
        tsum += __shfl_xor(tsum, off);
    }
    int lane = t & 63, wid = t >> 6;
    if (lane == 0) { sm[0][wid] = msum; sm[1][wid] = tsum; }
    __syncthreads();
    if (t == 0) {
        float M = 0.f, T = 0.f;
#pragma unroll
        for (int w = 0; w < 4; ++w) { M += sm[0][w]; T += sm[1][w]; }
        part[blockIdx.x] = make_float2(M, T);
    }
}

__global__ __launch_bounds__(64)
void final_loss(const float2* __restrict__ part, float* __restrict__ out) {
    const int t = threadIdx.x;
    float2 p = part[t];
    float M = p.x, T = p.y;
#pragma unroll
    for (int off = 32; off >= 1; off >>= 1) {
        M += __shfl_xor(M, off);
        T += __shfl_xor(T, off);
    }
    if (t == 0)
        out[0] = M / (float)(BATCH * LLEN) + 0.1f * (T / (float)(BATCH * N_DEATH));
}

// Fallback: single-block deterministic reduction (no extra scratch needed)
#define RTPB 1024
__global__ __launch_bounds__(RTPB)
void loss_kernel(const float* __restrict__ pred,
                 const float* __restrict__ tgt,
                 const float* __restrict__ topo,
                 float* __restrict__ out) {
    const int t = threadIdx.x;
    float msum = 0.f;
    const float4* p4 = (const float4*)pred;
    const float4* t4 = (const float4*)tgt;
    const int n4 = (BATCH * LLEN) / 4;   // 16384
    for (int e = t; e < n4; e += RTPB) {
        float4 a = p4[e], c = t4[e];
        float dx = a.x - c.x, dy = a.y - c.y, dz = a.z - c.z, dw = a.w - c.w;
        msum += dx * dx + dy * dy + dz * dz + dw * dw;
    }
    float tsum = 0.f;
    const int nt = BATCH * N_DEATH;      // 65440
    for (int e = t; e < nt; e += RTPB) {
        float d = topo[e] - topo[e + nt];
        tsum += d * d;
    }
    __shared__ float sm[2][RTPB / 64];
#pragma unroll
    for (int off = 32; off >= 1; off >>= 1) {
        msum += __shfl_xor(msum, off);
        tsum += __shfl_xor(tsum, off);
    }
    int lane = t & 63, wid = t >> 6;
    if (lane == 0) { sm[0][wid] = msum; sm[1][wid] = tsum; }
    __syncthreads();
    if (t == 0) {
        float M = 0.f, T = 0.f;
#pragma unroll
        for (int w = 0; w < RTPB / 64; ++w) { M += sm[0][w]; T += sm[1][w]; }
        out[0] = M / (float)(BATCH * LLEN) + 0.1f * (T / (float)nt);
    }
}

extern "C" void kernel_launch(void* const* d_in, const int* in_sizes, int n_in,
                              void* d_out, int out_size, void* d_ws, size_t ws_size,
                              hipStream_t stream) {
    const float* pred = (const float*)d_in[0];
    const float* tgt  = (const float*)d_in[1];
    const size_t topo_bytes = (size_t)64 * N_DEATH * 4;   // 523,520 B
    float* topo = (float*)d_ws;

    topo_kernel<<<2 * BATCH, TPB, 0, stream>>>(pred, tgt, topo);

    if (ws_size >= topo_bytes + 64 * sizeof(float2)) {
        float2* part = (float2*)((char*)d_ws + topo_bytes);
        partial_loss<<<64, 256, 0, stream>>>(pred, tgt, topo, part);
        final_loss<<<1, 64, 0, stream>>>(part, (float*)d_out);
    } else {
        loss_kernel<<<1, RTPB, 0, stream>>>(pred, tgt, topo, (float*)d_out);
    }
}

// Round 8
// 813.651 us; speedup vs baseline: 1.5237x; 1.5237x over previous
//
#include <hip/hip_runtime.h>
#include <math.h>

// Problem constants (reference: B=32, L=2048)
#define LLEN 2048
#define BATCH 32
#define N_PTS (LLEN - 2)     // 2046 embedded points
#define N_DEATH (LLEN - 3)   // 2045 MST edges / deaths
#define SORT_N 2048
#define TPB 256              // 4 waves, one per SIMD
#define PT 8                 // elements per thread
#define NW 4                 // waves per block
#define BIG 1e30f

// Wave64 unsigned-min via DPP (VALU pipe). Result valid in lane 63.
__device__ __forceinline__ unsigned dpp_umin6(unsigned v) {
    unsigned t;
    t = (unsigned)__builtin_amdgcn_update_dpp(-1, (int)v, 0x111, 0xF, 0xF, false); // row_shr:1
    v = t < v ? t : v;
    t = (unsigned)__builtin_amdgcn_update_dpp(-1, (int)v, 0x112, 0xF, 0xF, false); // row_shr:2
    v = t < v ? t : v;
    t = (unsigned)__builtin_amdgcn_update_dpp(-1, (int)v, 0x114, 0xF, 0xF, false); // row_shr:4
    v = t < v ? t : v;
    t = (unsigned)__builtin_amdgcn_update_dpp(-1, (int)v, 0x118, 0xF, 0xF, false); // row_shr:8
    v = t < v ? t : v;
    t = (unsigned)__builtin_amdgcn_update_dpp(-1, (int)v, 0x142, 0xF, 0xF, false); // row_bcast:15
    v = t < v ? t : v;
    t = (unsigned)__builtin_amdgcn_update_dpp(-1, (int)v, 0x143, 0xF, 0xF, false); // row_bcast:31
    v = t < v ? t : v;
    return v;
}

// One block per series. Prim with packed (d2|idx) u32 candidates; lock-free
// polled LDS mailbox — EXACT r5 protocol (proven 751 us):
//   * b32 slots only (r6's uint4 slots quadrupled poll LDS bandwidth: the
//     measured +420 cyc/iter regression; coords-in-mailbox is retired).
//   * lane 63 publishes straight off the DPP chain (no readlane/ballot on
//     the publish path — those delayed the publish and every poller with it).
//   * bit-11 sentinel clear prevents the all-visited-wave tag corruption
//     (r3 deadlock); pp[j] float4 broadcast read supplies winner coords.
// ROUND-8 DELTA: distance math in float2 so the backend can select
// v_pk_fma_f32/v_pk_add_f32 (gfx950 packed fp32) — halves the fp scan issue.
// Lowers to identical scalar ops if not selected (neutral downside).
__global__ __launch_bounds__(TPB)
void topo_kernel(const float* __restrict__ pred,
                 const float* __restrict__ tgt,
                 float* __restrict__ topo /* [64][N_DEATH] */) {
    __shared__ float4 pp[SORT_N];
    __shared__ float deaths[SORT_N];     // raw d2 during Prim
    __shared__ unsigned xslot[2 * NW];   // polled mailbox [buf][wave]

    const int b = blockIdx.x;
    const float* x = (b < BATCH) ? (pred + b * LLEN) : (tgt + (b - BATCH) * LLEN);
    const int t = threadIdx.x;
    const int lane = t & 63;
    const int wid = t >> 6;

    // mailbox init: tag bit = 1 mismatches iteration 0/1's expected tag 0
    if (t < 2 * NW) xslot[t] = 0x800u;

    float2 px[PT / 2], py[PT / 2], pz[PT / 2];   // element pairs (2s, 2s+1)
    unsigned m[PT];      // packed running min-distance (d2_hi20 | 0 | idx)
    unsigned vis = 0;    // bit s: vertex t*PT+s is visited (or padding)
    const unsigned base_idx = (unsigned)(t * PT);
#pragma unroll
    for (int s = 0; s < PT; ++s) {
        int idx = t * PT + s;
        bool valid = idx < N_PTS;
        float a0 = valid ? x[idx]     : 0.f;
        float a1 = valid ? x[idx + 1] : 0.f;
        float a2 = valid ? x[idx + 2] : 0.f;
        if (s & 1) { px[s >> 1].y = a0; py[s >> 1].y = a1; pz[s >> 1].y = a2; }
        else       { px[s >> 1].x = a0; py[s >> 1].x = a1; pz[s >> 1].x = a2; }
        pp[idx] = make_float4(a0, a1, a2, 0.f);
        m[s] = 0x7F800000u | (base_idx + s);    // +inf packed
        if (!valid || idx == 0) vis |= 1u << s; // pads + start vertex visited
    }
    __syncthreads();   // pp[] + mailbox init visible (only barrier before sort)

    float pjx = x[0], pjy = x[1], pjz = x[2];

    for (int i = 0; i < N_DEATH; ++i) {
        // fused: min-update with distance to j + masked local argmin.
        // float2 math -> v_pk_sub/v_pk_fma candidates; u32 path stays scalar.
        unsigned lv0 = 0xFFFFFFFFu, lv1 = 0xFFFFFFFFu;
        float2 pj2x = make_float2(pjx, pjx);
        float2 pj2y = make_float2(pjy, pjy);
        float2 pj2z = make_float2(pjz, pjz);
#pragma unroll
        for (int p = 0; p < PT / 2; ++p) {
            float2 dx = px[p] - pj2x;
            float2 dy = py[p] - pj2y;
            float2 dz = pz[p] - pj2z;
            float2 d2 = dx * dx + dy * dy + dz * dz;
            const int s0 = 2 * p, s1 = 2 * p + 1;
            unsigned pk0 = (__float_as_uint(d2.x) & 0xFFFFF000u) | (base_idx + s0);
            unsigned pk1 = (__float_as_uint(d2.y) & 0xFFFFF000u) | (base_idx + s1);
            unsigned nm0 = m[s0] < pk0 ? m[s0] : pk0;
            unsigned nm1 = m[s1] < pk1 ? m[s1] : pk1;
            m[s0] = nm0; m[s1] = nm1;
            unsigned e0 = (unsigned)__builtin_amdgcn_sbfe((int)vis, s0, 1);
            unsigned e1 = (unsigned)__builtin_amdgcn_sbfe((int)vis, s1, 1);
            unsigned c0 = nm0 | e0;
            unsigned c1 = nm1 | e1;
            lv0 = lv0 < c0 ? lv0 : c0;   // min-chains shaped for v_min3_u32
            lv1 = lv1 < c1 ? lv1 : c1;
        }
        unsigned lv = lv0 < lv1 ? lv0 : lv1;
        unsigned wmin = dpp_umin6(lv);           // valid in lane 63
        const unsigned tag = ((unsigned)(i >> 1) & 1u) << 11;
        const int base = (i & 1) * NW;
        // lane 63 publishes straight away: clear bit 11 (all-visited sentinel
        // protection), stamp tag.
        if (lane == 63) {
            unsigned clean = (wmin & 0xFFFFF7FFu) | tag;
            __hip_atomic_store(&xslot[base + wid], clean,
                               __ATOMIC_RELAXED, __HIP_MEMORY_SCOPE_WORKGROUP);
        }
        // poll: 4 relaxed b32 loads back-to-back -> one waitcnt per round
        unsigned v0, v1, v2, v3;
        for (;;) {
            v0 = __hip_atomic_load(&xslot[base + 0], __ATOMIC_RELAXED, __HIP_MEMORY_SCOPE_WORKGROUP);
            v1 = __hip_atomic_load(&xslot[base + 1], __ATOMIC_RELAXED, __HIP_MEMORY_SCOPE_WORKGROUP);
            v2 = __hip_atomic_load(&xslot[base + 2], __ATOMIC_RELAXED, __HIP_MEMORY_SCOPE_WORKGROUP);
            v3 = __hip_atomic_load(&xslot[base + 3], __ATOMIC_RELAXED, __HIP_MEMORY_SCOPE_WORKGROUP);
            unsigned bad = ((v0 ^ tag) | (v1 ^ tag) | (v2 ^ tag) | (v3 ^ tag)) & 0x800u;
            if (!bad) break;
        }
        unsigned w01 = v0 < v1 ? v0 : v1;
        unsigned w23 = v2 < v3 ? v2 : v3;
        unsigned win = w01 < w23 ? w01 : w23;
        int j = (int)(win & 0x7FFu);
        // mark new j visited in its owner thread
        vis |= (t == (j >> 3)) ? (1u << (j & 7)) : 0u;
        float4 pj = pp[j];                       // broadcast read, conflict-free
        pjx = pj.x; pjy = pj.y; pjz = pj.z;
        if (t == 0) deaths[i] = __uint_as_float(win & 0xFFFFF000u); // raw d2
    }

    // pad then bitonic sort DESCENDING on d2 (sqrt is monotone -> same order)
    if (t < SORT_N - N_DEATH) deaths[N_DEATH + t] = -BIG;
    __syncthreads();

    for (int k = 2; k <= SORT_N; k <<= 1) {
        for (int jj = k >> 1; jj > 0; jj >>= 1) {
#pragma unroll
            for (int s = 0; s < SORT_N / TPB; ++s) {
                int ii = t + s * TPB;
                int ixj = ii ^ jj;
                if (ixj > ii) {
                    float a = deaths[ii], c = deaths[ixj];
                    bool descBlock = ((ii & k) == 0);
                    bool doSwap = descBlock ? (a < c) : (a > c);
                    if (doSwap) { deaths[ii] = c; deaths[ixj] = a; }
                }
            }
            __syncthreads();
        }
    }

    for (int e = t; e < N_DEATH; e += TPB)
        topo[b * N_DEATH + e] = sqrtf(deaths[e]);   // sqrt deferred to here
}

// Two-stage loss (used when d_ws has room for the 512 B partials buffer)
__global__ __launch_bounds__(256)
void partial_loss(const float* __restrict__ pred,
                  const float* __restrict__ tgt,
                  const float* __restrict__ topo,
                  float2* __restrict__ part) {
    const int t = threadIdx.x;
    const int gid = blockIdx.x * 256 + t;       // 0..16383
    const float4* p4 = (const float4*)pred;
    const float4* t4 = (const float4*)tgt;
    float4 a = p4[gid], c = t4[gid];            // exactly one float4 per thread
    float dx = a.x - c.x, dy = a.y - c.y, dz = a.z - c.z, dw = a.w - c.w;
    float msum = dx * dx + dy * dy + dz * dz + dw * dw;
    float tsum = 0.f;
    const int nt = BATCH * N_DEATH;             // 65440
    for (int e = gid; e < nt; e += 64 * 256) {
        float d = topo[e] - topo[e + nt];
        tsum += d * d;
    }
    __shared__ float sm[2][4];
#pragma unroll
    for (int off = 32; off >= 1; off >>= 1) {
        msum += __shfl_xor(msum, off);
        tsum += __shfl_xor(tsum, off);
    }
    int lane = t & 63, wid = t >> 6;
    if (lane == 0) { sm[0][wid] = msum; sm[1][wid] = tsum; }
    __syncthreads();
    if (t == 0) {
        float M = 0.f, T = 0.f;
#pragma unroll
        for (int w = 0; w < 4; ++w) { M += sm[0][w]; T += sm[1][w]; }
        part[blockIdx.x] = make_float2(M, T);
    }
}

__global__ __launch_bounds__(64)
void final_loss(const float2* __restrict__ part, float* __restrict__ out) {
    const int t = threadIdx.x;
    float2 p = part[t];
    float M = p.x, T = p.y;
#pragma unroll
    for (int off = 32; off >= 1; off >>= 1) {
        M += __shfl_xor(M, off);
        T += __shfl_xor(T, off);
    }
    if (t == 0)
        out[0] = M / (float)(BATCH * LLEN) + 0.1f * (T / (float)(BATCH * N_DEATH));
}

// Fallback: single-block deterministic reduction (no extra scratch needed)
#define RTPB 1024
__global__ __launch_bounds__(RTPB)
void loss_kernel(const float* __restrict__ pred,
                 const float* __restrict__ tgt,
                 const float* __restrict__ topo,
                 float* __restrict__ out) {
    const int t = threadIdx.x;
    float msum = 0.f;
    const float4* p4 = (const float4*)pred;
    const float4* t4 = (const float4*)tgt;
    const int n4 = (BATCH * LLEN) / 4;   // 16384
    for (int e = t; e < n4; e += RTPB) {
        float4 a = p4[e], c = t4[e];
        float dx = a.x - c.x, dy = a.y - c.y, dz = a.z - c.z, dw = a.w - c.w;
        msum += dx * dx + dy * dy + dz * dz + dw * dw;
    }
    float tsum = 0.f;
    const int nt = BATCH * N_DEATH;      // 65440
    for (int e = t; e < nt; e += RTPB) {
        float d = topo[e] - topo[e + nt];
        tsum += d * d;
    }
    __shared__ float sm[2][RTPB / 64];
#pragma unroll
    for (int off = 32; off >= 1; off >>= 1) {
        msum += __shfl_xor(msum, off);
        tsum += __shfl_xor(tsum, off);
    }
    int lane = t & 63, wid = t >> 6;
    if (lane == 0) { sm[0][wid] = msum; sm[1][wid] = tsum; }
    __syncthreads();
    if (t == 0) {
        float M = 0.f, T = 0.f;
#pragma unroll
        for (int w = 0; w < RTPB / 64; ++w) { M += sm[0][w]; T += sm[1][w]; }
        out[0] = M / (float)(BATCH * LLEN) + 0.1f * (T / (float)nt);
    }
}

extern "C" void kernel_launch(void* const* d_in, const int* in_sizes, int n_in,
                              void* d_out, int out_size, void* d_ws, size_t ws_size,
                              hipStream_t stream) {
    const float* pred = (const float*)d_in[0];
    const float* tgt  = (const float*)d_in[1];
    const size_t topo_bytes = (size_t)64 * N_DEATH * 4;   // 523,520 B
    float* topo = (float*)d_ws;

    topo_kernel<<<2 * BATCH, TPB, 0, stream>>>(pred, tgt, topo);

    if (ws_size >= topo_bytes + 64 * sizeof(float2)) {
        float2* part = (float2*)((char*)d_ws + topo_bytes);
        partial_loss<<<64, 256, 0, stream>>>(pred, tgt, topo, part);
        final_loss<<<1, 64, 0, stream>>>(part, (float*)d_out);
    } else {
        loss_kernel<<<1, RTPB, 0, stream>>>(pred, tgt, topo, (float*)d_out);
    }
}